// Round 12
// baseline (281.778 us; speedup 1.0000x reference)
//
#include <hip/hip_runtime.h>

// SparseMLP (grouped GEMM MoE): out = gelu_tanh(x @ w1^T) @ w2, per expert.
// R12: DIAGNOSTIC round. Kernels identical to R11 (known-good 205us).
// A pure-read microbenchmark over w1 (512 MB, nt dwordx4, grid-stride) is
// prepended so dur_us - 205 = t_read measures the HBM READ-stream ceiling
// on this chip (we only have write-fill 6.8 TB/s and copy 6.29 TB/s data).
// If t_read ~80-88us -> reads can do ~6+ TB/s and the GEMM gap is ours.
// If t_read ~95-105us -> read ceiling ~5.3 TB/s; GEMMs are at roofline.
// Result is kept live per-thread via asm sink (rule 17); nothing written.

typedef __attribute__((ext_vector_type(8))) short short8;    // 8 bf16 = 4 VGPR
typedef __attribute__((ext_vector_type(4))) float f32x4;     // MFMA acc / ld
typedef __attribute__((ext_vector_type(8))) unsigned short ushort8;

#define NE   64
#define CAPT 64
#define HD   1024
#define FD   2048

// fp32 -> bf16 round-to-nearest-even
__device__ __forceinline__ unsigned short f2bf(float f) {
  union { float f; unsigned u; } v; v.f = f;
  unsigned r = v.u + 0x7FFFu + ((v.u >> 16) & 1u);
  return (unsigned short)(r >> 16);
}

// gelu_tanh(v) = v * sigmoid(2*0.79788456*(v + 0.044715 v^3))  (exact rewrite)
__device__ __forceinline__ float gelu_t(float v) {
  float u = 1.5957691216057308f * (v + 0.044715f * v * v * v);
  return v / (1.0f + __expf(-u));
}

// XOR swizzle (T2) for a [rows][64]-bf16 tile (row stride 128B): pass 2.
__device__ __forceinline__ int swz(int row, int kbyte) {
  return row * 128 + (kbyte ^ ((row & 7) << 4));
}
// XOR swizzle for a [rows][128]-bf16 tile (row stride 256B): pass 1 (BK=128).
__device__ __forceinline__ int swz2(int row, int kbyte) {
  return row * 256 + (kbyte ^ ((row & 7) << 4));
}

__device__ __forceinline__ void cvt_wr4(unsigned char* dst, f32x4 v) {
  uint2 p;
  p.x = (unsigned)f2bf(v.x) | ((unsigned)f2bf(v.y) << 16);
  p.y = (unsigned)f2bf(v.z) | ((unsigned)f2bf(v.w) << 16);
  *(uint2*)dst = p;   // ds_write_b64
}

// Raw barrier with LDS-only drain (T4).
__device__ __forceinline__ void tile_barrier() {
  asm volatile("s_waitcnt lgkmcnt(0)" ::: "memory");
  __builtin_amdgcn_s_barrier();
  __builtin_amdgcn_sched_barrier(0);
}

// Bijective XCD swizzle (T1): same-expert blocks share an L2.
__device__ __forceinline__ int xcd_swz(int bid, int grid) {
  return (bid & 7) * (grid >> 3) + (bid >> 3);
}

// ------------------------------------------------------------ read bench ---
// Pure HBM read-stream probe: 512 MB of w1 via nt dwordx4, grid-stride,
// coalesced 1KB/wave-instruction. Per-thread result kept live via asm sink
// (no DCE, no stores, no side effects).
__global__ __launch_bounds__(256)
void read_bench(const float* __restrict__ w) {
  const size_t n4 = (size_t)NE * FD * HD / 4;          // 33.55M f32x4
  const size_t stride = (size_t)gridDim.x * 256;
  f32x4 s = {};
  for (size_t i = (size_t)blockIdx.x * 256 + threadIdx.x; i < n4; i += stride) {
    f32x4 v = __builtin_nontemporal_load((const f32x4*)w + i);
    s += v;
  }
  float r = s.x + s.y + s.z + s.w;
  asm volatile("" :: "v"(r));                          // keep loads live
}

// ---------------------------------------------------------------- pass 1 ---
// C1[64,2048] = x_e[64,1024] @ w1_e[2048,1024]^T  (NT: both K-contiguous)
// grid = E*(F/64)=2048; tile BM=64 BN=64 BK=128; 8 waves (2x4), wave 32x16.
#define P1_TSZ (64 * 256)          // one [64][128]-bf16 buffer, bytes
__global__ __launch_bounds__(512, 4)
void moe_pass1(const float* __restrict__ x, const float* __restrict__ w1,
               unsigned short* __restrict__ hb) {
  __shared__ __align__(16) unsigned char sA[2 * P1_TSZ];   // 32 KB
  __shared__ __align__(16) unsigned char sB[2 * P1_TSZ];   // 32 KB
  const int bid = xcd_swz(blockIdx.x, NE * 32);
  const int e = bid >> 5, nb = bid & 31;
  const int t = threadIdx.x, lane = t & 63, wid = t >> 6;
  const int wm = wid >> 2, wn = wid & 3;
  const int lr = lane & 15, lk16 = (lane >> 4) * 16;

  const float* xg  = x  + (size_t)e * CAPT * HD;
  const float* w1g = w1 + ((size_t)e * FD + (size_t)nb * 64) * HD;

  f32x4 acc[2] = {};

  f32x4 ra0[4], ra1[4], rb0[4], rb1[4];
  auto loadA = [&](f32x4 (&ra)[4], int k0) {
    #pragma unroll
    for (int i = 0; i < 4; ++i) {
      int u = t + i * 512;
      ra[i] = *(const f32x4*)(xg + (u >> 5) * HD + k0 + (u & 31) * 4);
    }
  };
  auto loadB = [&](f32x4 (&rb)[4], int k0) {
    #pragma unroll
    for (int i = 0; i < 4; ++i) {
      int u = t + i * 512;
      rb[i] = __builtin_nontemporal_load(
          (const f32x4*)(w1g + (u >> 5) * HD + k0 + (u & 31) * 4));
    }
  };
  auto writeT = [&](unsigned char* a, unsigned char* b,
                    f32x4 (&ra)[4], f32x4 (&rb)[4]) {
    #pragma unroll
    for (int i = 0; i < 4; ++i) {
      int u = t + i * 512;
      cvt_wr4(a + swz2(u >> 5, (u & 31) * 8), ra[i]);
    }
    #pragma unroll
    for (int i = 0; i < 4; ++i) {
      int u = t + i * 512;
      cvt_wr4(b + swz2(u >> 5, (u & 31) * 8), rb[i]);
    }
  };

  const int NK = HD / 128;                                   // 8 K-steps
  loadA(ra0, 0);   loadB(rb0, 0);
  writeT(sA, sB, ra0, rb0);
  loadA(ra1, 128); loadB(rb1, 128);
  loadA(ra0, 256); loadB(rb0, 256);
  tile_barrier();

  int cur = 0;
  auto step = [&](int ks, f32x4 (&raS)[4], f32x4 (&rbS)[4]) {
    unsigned char* cA = sA + cur * P1_TSZ;
    unsigned char* cB = sB + cur * P1_TSZ;
    if (ks + 1 < NK) writeT(sA + (cur ^ 1) * P1_TSZ, sB + (cur ^ 1) * P1_TSZ,
                            raS, rbS);
    if (ks + 3 < NK) { loadA(raS, (ks + 3) * 128); loadB(rbS, (ks + 3) * 128); }

    #pragma unroll
    for (int kk = 0; kk < 4; ++kk) {                         // K=128 = 4x32
      short8 af0 = *(const short8*)(cA + swz2(wm * 32 + lr,      kk * 64 + lk16));
      short8 af1 = *(const short8*)(cA + swz2(wm * 32 + 16 + lr, kk * 64 + lk16));
      short8 bfr = *(const short8*)(cB + swz2(wn * 16 + lr,      kk * 64 + lk16));
      acc[0] = __builtin_amdgcn_mfma_f32_16x16x32_bf16(af0, bfr, acc[0], 0, 0, 0);
      acc[1] = __builtin_amdgcn_mfma_f32_16x16x32_bf16(af1, bfr, acc[1], 0, 0, 0);
    }
    tile_barrier();
    cur ^= 1;
  };
  #pragma unroll 1
  for (int ks = 0; ks < NK; ks += 2) {
    step(ks,     ra1, rb1);
    step(ks + 1, ra0, rb0);
  }

  unsigned short* hp = hb + (size_t)e * CAPT * FD + nb * 64;
  #pragma unroll
  for (int fm = 0; fm < 2; ++fm)
    #pragma unroll
    for (int j = 0; j < 4; ++j) {
      int m = wm * 32 + fm * 16 + (lane >> 4) * 4 + j;
      int f = wn * 16 + lr;
      hp[(size_t)m * FD + f] = f2bf(gelu_t(acc[fm][j]));
    }
}

#define A_SZ (64 * 128)
#define B_SZ (128 * 128)

// ---------------------------------------------------------------- pass 2 ---
__global__ __launch_bounds__(512, 4)
void moe_pass2(const unsigned short* __restrict__ hb, const float* __restrict__ w2,
               float* __restrict__ out) {
  __shared__ __align__(16) unsigned char sA[2 * A_SZ];
  __shared__ __align__(16) unsigned char sB[2 * B_SZ];
  const int bid = xcd_swz(blockIdx.x, NE * 8);
  const int e = bid >> 3, nb = bid & 7;
  const int t = threadIdx.x, lane = t & 63, wid = t >> 6;
  const int wm = wid >> 2, wn = wid & 3;
  const int lr = lane & 15, lkb = (lane >> 4) * 16;

  const unsigned short* hg = hb + (size_t)e * CAPT * FD;
  const float* w2g = w2 + (size_t)e * FD * HD + nb * 128;

  f32x4 acc[2][2] = {};

  const int ar = t >> 3, ac = t & 7;
  const int bn = t & 127, bkg = t >> 7;

  ushort8 rav0, rav1;
  float rbv0[16], rbv1[16];
  auto loadA = [&](ushort8& rav, int f0) {
    rav = *(const ushort8*)(hg + (size_t)ar * FD + f0 + ac * 8);
  };
  auto loadB = [&](float (&rbv)[16], int f0) {
    #pragma unroll
    for (int i = 0; i < 4; ++i)
      #pragma unroll
      for (int j = 0; j < 4; ++j)
        rbv[i * 4 + j] = __builtin_nontemporal_load(
            w2g + (size_t)(f0 + bkg * 16 + i * 4 + j) * HD + bn);
  };
  auto writeT = [&](unsigned char* a, unsigned char* b,
                    ushort8& rav, float (&rbv)[16]) {
    *(ushort8*)(a + swz(ar, ac * 16)) = rav;
    #pragma unroll
    for (int i = 0; i < 4; ++i) {
      uint2 p;
      p.x = (unsigned)f2bf(rbv[i * 4 + 0]) | ((unsigned)f2bf(rbv[i * 4 + 1]) << 16);
      p.y = (unsigned)f2bf(rbv[i * 4 + 2]) | ((unsigned)f2bf(rbv[i * 4 + 3]) << 16);
      *(uint2*)(b + swz(bn, (bkg * 16 + i * 4) * 2)) = p;
    }
  };

  const int NK = FD / 64;
  loadA(rav0, 0);   loadB(rbv0, 0);
  writeT(sA, sB, rav0, rbv0);
  loadA(rav1, 64);  loadB(rbv1, 64);
  loadA(rav0, 128); loadB(rbv0, 128);
  tile_barrier();

  int cur = 0;
  auto step = [&](int ks, ushort8& ravS, float (&rbvS)[16]) {
    unsigned char* cA = sA + cur * A_SZ;
    unsigned char* cB = sB + cur * B_SZ;
    if (ks + 1 < NK) writeT(sA + (cur ^ 1) * A_SZ, sB + (cur ^ 1) * B_SZ,
                            ravS, rbvS);
    if (ks + 3 < NK) { loadA(ravS, (ks + 3) * 64); loadB(rbvS, (ks + 3) * 64); }

    short8 af[2][2], bf[2][2];
    #pragma unroll
    for (int fm = 0; fm < 2; ++fm)
      #pragma unroll
      for (int kk = 0; kk < 2; ++kk)
        af[fm][kk] = *(const short8*)(cA + swz(wm * 32 + fm * 16 + lr, kk * 64 + lkb));
    #pragma unroll
    for (int fn = 0; fn < 2; ++fn)
      #pragma unroll
      for (int kk = 0; kk < 2; ++kk)
        bf[fn][kk] = *(const short8*)(cB + swz(wn * 32 + fn * 16 + lr, kk * 64 + lkb));
    #pragma unroll
    for (int fm = 0; fm < 2; ++fm)
      #pragma unroll
      for (int fn = 0; fn < 2; ++fn) {
        acc[fm][fn] = __builtin_amdgcn_mfma_f32_16x16x32_bf16(af[fm][0], bf[fn][0], acc[fm][fn], 0, 0, 0);
        acc[fm][fn] = __builtin_amdgcn_mfma_f32_16x16x32_bf16(af[fm][1], bf[fn][1], acc[fm][fn], 0, 0, 0);
      }
    tile_barrier();
    cur ^= 1;
  };
  #pragma unroll 1
  for (int ks = 0; ks < NK; ks += 2) {
    step(ks,     rav1, rbv1);
    step(ks + 1, rav0, rbv0);
  }

  float* op = out + (size_t)e * CAPT * HD + nb * 128;
  #pragma unroll
  for (int fm = 0; fm < 2; ++fm)
    #pragma unroll
    for (int fn = 0; fn < 2; ++fn)
      #pragma unroll
      for (int j = 0; j < 4; ++j) {
        int m = wm * 32 + fm * 16 + (lane >> 4) * 4 + j;
        int n = wn * 32 + fn * 16 + lr;
        __builtin_nontemporal_store(acc[fm][fn][j], op + (size_t)m * HD + n);
      }
}

extern "C" void kernel_launch(void* const* d_in, const int* in_sizes, int n_in,
                              void* d_out, int out_size, void* d_ws, size_t ws_size,
                              hipStream_t stream) {
  const float* x  = (const float*)d_in[0];
  const float* w1 = (const float*)d_in[1];
  const float* w2 = (const float*)d_in[2];
  float* out = (float*)d_out;
  unsigned short* hb = (unsigned short*)d_ws;   // h: E*CAP*F bf16 = 16.78 MB
  (void)in_sizes; (void)n_in; (void)out_size; (void)ws_size;

  // Diagnostic: pure read-stream probe over w1 (512 MB). dur-205us = t_read.
  read_bench<<<dim3(2048), dim3(256), 0, stream>>>(w1);
  moe_pass1<<<dim3(NE * (FD / 64)), dim3(512), 0, stream>>>(x, w1, hb);
  moe_pass2<<<dim3(NE * (HD / 128)), dim3(512), 0, stream>>>(hb, w2, out);
}

// Round 14
// 230.773 us; speedup vs baseline: 1.2210x; 1.2210x over previous
//
#include <hip/hip_runtime.h>

// SparseMLP (grouped GEMM MoE): out = gelu_tanh(x @ w1^T) @ w2, per expert.
// E=64, CAP=64, H=1024, F=2048, fp32 in/out.
// R14 = R13 with the staging bug fixed: x_e prologue now stages ALL 64x1024
// (32 iters of 512x16B chunks; R13 did 8 iters = 1/4 of x_e -> NaN from
// uninitialized LDS). Structure: pass1 stages x_e ONCE in LDS (128KB bf16,
// swizzled), then each wave free-runs its K-loop with NO barriers; w1
// B-fragments nt-loaded DIRECT from global (32B/lane), v_cvt_pk_bf16_f32,
// MFMA, 2-deep static ping-pong. 256 blocks (1/CU). Pass 2 = R11.

typedef __attribute__((ext_vector_type(8))) short short8;    // 8 bf16 = 4 VGPR
typedef __attribute__((ext_vector_type(4))) float f32x4;     // MFMA acc / ld
typedef __attribute__((ext_vector_type(4))) unsigned int uint4v;
typedef __attribute__((ext_vector_type(8))) unsigned short ushort8;

#define NE   64
#define CAPT 64
#define HD   1024
#define FD   2048

// fp32 -> bf16 round-to-nearest-even
__device__ __forceinline__ unsigned short f2bf(float f) {
  union { float f; unsigned u; } v; v.f = f;
  unsigned r = v.u + 0x7FFFu + ((v.u >> 16) & 1u);
  return (unsigned short)(r >> 16);
}

// gelu_tanh(v) = v * sigmoid(2*0.79788456*(v + 0.044715 v^3))  (exact rewrite)
__device__ __forceinline__ float gelu_t(float v) {
  float u = 1.5957691216057308f * (v + 0.044715f * v * v * v);
  return v / (1.0f + __expf(-u));
}

// pack 8 f32 (two f32x4) -> short8 bf16 via v_cvt_pk_bf16_f32 (RNE)
__device__ __forceinline__ short8 pack_bf16x8(f32x4 a, f32x4 b) {
  union { uint4v u; short8 s; } r;
  unsigned d0, d1, d2, d3;
  asm("v_cvt_pk_bf16_f32 %0,%1,%2" : "=v"(d0) : "v"(a.x), "v"(a.y));
  asm("v_cvt_pk_bf16_f32 %0,%1,%2" : "=v"(d1) : "v"(a.z), "v"(a.w));
  asm("v_cvt_pk_bf16_f32 %0,%1,%2" : "=v"(d2) : "v"(b.x), "v"(b.y));
  asm("v_cvt_pk_bf16_f32 %0,%1,%2" : "=v"(d3) : "v"(b.z), "v"(b.w));
  r.u.x = d0; r.u.y = d1; r.u.z = d2; r.u.w = d3;
  return r.s;
}

// XOR swizzle (T2) for a [rows][64]-bf16 tile (row stride 128B): pass 2.
__device__ __forceinline__ int swz(int row, int kbyte) {
  return row * 128 + (kbyte ^ ((row & 7) << 4));
}

__device__ __forceinline__ void cvt_wr4(unsigned char* dst, f32x4 v) {
  uint2 p;
  p.x = (unsigned)f2bf(v.x) | ((unsigned)f2bf(v.y) << 16);
  p.y = (unsigned)f2bf(v.z) | ((unsigned)f2bf(v.w) << 16);
  *(uint2*)dst = p;   // ds_write_b64
}

// Raw barrier with LDS-only drain (T4), pass-2 loop.
__device__ __forceinline__ void tile_barrier() {
  asm volatile("s_waitcnt lgkmcnt(0)" ::: "memory");
  __builtin_amdgcn_s_barrier();
  __builtin_amdgcn_sched_barrier(0);
}

// Bijective XCD swizzle (T1): same-expert blocks share an L2.
__device__ __forceinline__ int xcd_swz(int bid, int grid) {
  return (bid & 7) * (grid >> 3) + (bid >> 3);
}

// ---------------------------------------------------------------- pass 1 ---
// h[64,2048] = gelu(x_e[64,1024] @ w1_e[2048,1024]^T), bf16.
// grid = E*4 = 256 blocks (1/CU), 512 thr. Block: expert e, F-slice of 512.
// x_e in LDS (bf16, swizzled, 128KB). Wave w owns F-cols w*64..+63:
// 4 m-tiles x 4 n-tiles of 16x16, K-loop 32 steps, NO barriers.
__global__ __launch_bounds__(512, 2)
void moe_pass1(const float* __restrict__ x, const float* __restrict__ w1,
               unsigned short* __restrict__ hb) {
  __shared__ __align__(16) unsigned char sX[64 * 2048];    // 128 KB
  const int sb = xcd_swz(blockIdx.x, NE * 4);
  const int e = sb >> 2, slice = sb & 3;
  const int t = threadIdx.x, lane = t & 63, wid = t >> 6;
  const int lr = lane & 15, kg = lane >> 4;

  const float* xg  = x + (size_t)e * CAPT * HD;
  // wave's w1 rows: slice*512 + wid*64 .. +63
  const float* w1g = w1 + ((size_t)e * FD + (size_t)slice * 512 + wid * 64) * HD;

  // ---- prologue: stage x_e (fp32 -> bf16, swizzled) ----
  // 64 rows x 256 chunks (4 f32 -> 8B bf16) = 16384 chunks; 32/thread.
  #pragma unroll
  for (int i = 0; i < 32; ++i) {
    int u = t + i * 512;
    int r = u >> 8, c = u & 255;
    f32x4 v = *(const f32x4*)(xg + r * HD + c * 4);
    cvt_wr4(sX + r * 2048 + ((c * 8) ^ ((r & 7) << 4)), v);
  }
  __syncthreads();                       // x tile ready; last barrier.

  f32x4 acc[4][4] = {};                  // [m-tile][n-tile]

  // B reg sets: 4 n-tiles x 2 f32x4 (32B/lane = w1[n][k0+kg*8..+7])
  f32x4 b0[8], b1[8];
  auto loadB = [&](f32x4 (&bs)[8], int k0) {
    #pragma unroll
    for (int j = 0; j < 4; ++j) {
      const float* rp = w1g + (size_t)(j * 16 + lr) * HD + k0 + kg * 8;
      bs[j * 2]     = __builtin_nontemporal_load((const f32x4*)rp);
      bs[j * 2 + 1] = __builtin_nontemporal_load((const f32x4*)rp + 1);
    }
  };
  // one K=32 step: consume set, refill it for ks+2, read A frags, 16 MFMA
  auto step = [&](f32x4 (&bs)[8], int ks) {
    short8 bf[4];
    #pragma unroll
    for (int j = 0; j < 4; ++j) bf[j] = pack_bf16x8(bs[j * 2], bs[j * 2 + 1]);
    if (ks + 2 < 32) loadB(bs, (ks + 2) * 32);
    short8 af[4];
    #pragma unroll
    for (int mt = 0; mt < 4; ++mt) {
      int row = mt * 16 + lr;
      af[mt] = *(const short8*)(sX + row * 2048 +
                                ((ks * 64 + kg * 16) ^ ((row & 7) << 4)));
    }
    #pragma unroll
    for (int mt = 0; mt < 4; ++mt)
      #pragma unroll
      for (int j = 0; j < 4; ++j)
        acc[mt][j] = __builtin_amdgcn_mfma_f32_16x16x32_bf16(af[mt], bf[j], acc[mt][j], 0, 0, 0);
  };

  loadB(b0, 0);
  loadB(b1, 32);
  #pragma unroll 1
  for (int ks = 0; ks < 32; ks += 2) {   // free-running, no barriers
    step(b0, ks);
    step(b1, ks + 1);
  }

  // epilogue: gelu, cvt, store h. C/D: col=lane&15, row=(lane>>4)*4+j
  unsigned short* hp = hb + (size_t)e * CAPT * FD + slice * 512 + wid * 64;
  #pragma unroll
  for (int mt = 0; mt < 4; ++mt)
    #pragma unroll
    for (int j = 0; j < 4; ++j)
      #pragma unroll
      for (int jj = 0; jj < 4; ++jj) {
        int m = mt * 16 + (lane >> 4) * 4 + jj;
        int f = j * 16 + lr;
        hp[(size_t)m * FD + f] = f2bf(gelu_t(acc[mt][j][jj]));
      }
}

#define A_SZ (64 * 128)
#define B_SZ (128 * 128)

// ---------------------------------------------------------------- pass 2 ---
// C2[64,1024] = h_e[64,2048](bf16) @ w2_e[2048,1024]  (NN: w2 transposed at
// stage time into LDS [n][k]). Unchanged R11 (3-deep static ping-pong).
__global__ __launch_bounds__(512, 4)
void moe_pass2(const unsigned short* __restrict__ hb, const float* __restrict__ w2,
               float* __restrict__ out) {
  __shared__ __align__(16) unsigned char sA[2 * A_SZ];
  __shared__ __align__(16) unsigned char sB[2 * B_SZ];
  const int bid = xcd_swz(blockIdx.x, NE * 8);
  const int e = bid >> 3, nb = bid & 7;
  const int t = threadIdx.x, lane = t & 63, wid = t >> 6;
  const int wm = wid >> 2, wn = wid & 3;
  const int lr = lane & 15, lkb = (lane >> 4) * 16;

  const unsigned short* hg = hb + (size_t)e * CAPT * FD;
  const float* w2g = w2 + (size_t)e * FD * HD + nb * 128;

  f32x4 acc[2][2] = {};

  const int ar = t >> 3, ac = t & 7;
  const int bn = t & 127, bkg = t >> 7;

  ushort8 rav0, rav1;
  float rbv0[16], rbv1[16];
  auto loadA = [&](ushort8& rav, int f0) {
    rav = *(const ushort8*)(hg + (size_t)ar * FD + f0 + ac * 8);
  };
  auto loadB = [&](float (&rbv)[16], int f0) {
    #pragma unroll
    for (int i = 0; i < 4; ++i)
      #pragma unroll
      for (int j = 0; j < 4; ++j)
        rbv[i * 4 + j] = __builtin_nontemporal_load(
            w2g + (size_t)(f0 + bkg * 16 + i * 4 + j) * HD + bn);
  };
  auto writeT = [&](unsigned char* a, unsigned char* b,
                    ushort8& rav, float (&rbv)[16]) {
    *(ushort8*)(a + swz(ar, ac * 16)) = rav;
    #pragma unroll
    for (int i = 0; i < 4; ++i) {
      uint2 p;
      p.x = (unsigned)f2bf(rbv[i * 4 + 0]) | ((unsigned)f2bf(rbv[i * 4 + 1]) << 16);
      p.y = (unsigned)f2bf(rbv[i * 4 + 2]) | ((unsigned)f2bf(rbv[i * 4 + 3]) << 16);
      *(uint2*)(b + swz(bn, (bkg * 16 + i * 4) * 2)) = p;
    }
  };

  const int NK = FD / 64;
  loadA(rav0, 0);   loadB(rbv0, 0);
  writeT(sA, sB, rav0, rbv0);
  loadA(rav1, 64);  loadB(rbv1, 64);
  loadA(rav0, 128); loadB(rbv0, 128);
  tile_barrier();

  int cur = 0;
  auto step = [&](int ks, ushort8& ravS, float (&rbvS)[16]) {
    unsigned char* cA = sA + cur * A_SZ;
    unsigned char* cB = sB + cur * B_SZ;
    if (ks + 1 < NK) writeT(sA + (cur ^ 1) * A_SZ, sB + (cur ^ 1) * B_SZ,
                            ravS, rbvS);
    if (ks + 3 < NK) { loadA(ravS, (ks + 3) * 64); loadB(rbvS, (ks + 3) * 64); }

    short8 af[2][2], bf[2][2];
    #pragma unroll
    for (int fm = 0; fm < 2; ++fm)
      #pragma unroll
      for (int kk = 0; kk < 2; ++kk)
        af[fm][kk] = *(const short8*)(cA + swz(wm * 32 + fm * 16 + lr, kk * 64 + lkb));
    #pragma unroll
    for (int fn = 0; fn < 2; ++fn)
      #pragma unroll
      for (int kk = 0; kk < 2; ++kk)
        bf[fn][kk] = *(const short8*)(cB + swz(wn * 32 + fn * 16 + lr, kk * 64 + lkb));
    #pragma unroll
    for (int fm = 0; fm < 2; ++fm)
      #pragma unroll
      for (int fn = 0; fn < 2; ++fn) {
        acc[fm][fn] = __builtin_amdgcn_mfma_f32_16x16x32_bf16(af[fm][0], bf[fn][0], acc[fm][fn], 0, 0, 0);
        acc[fm][fn] = __builtin_amdgcn_mfma_f32_16x16x32_bf16(af[fm][1], bf[fn][1], acc[fm][fn], 0, 0, 0);
      }
    tile_barrier();
    cur ^= 1;
  };
  #pragma unroll 1
  for (int ks = 0; ks < NK; ks += 2) {
    step(ks,     rav1, rbv1);
    step(ks + 1, rav0, rbv0);
  }

  float* op = out + (size_t)e * CAPT * HD + nb * 128;
  #pragma unroll
  for (int fm = 0; fm < 2; ++fm)
    #pragma unroll
    for (int fn = 0; fn < 2; ++fn)
      #pragma unroll
      for (int j = 0; j < 4; ++j) {
        int m = wm * 32 + fm * 16 + (lane >> 4) * 4 + j;
        int n = wn * 32 + fn * 16 + lr;
        __builtin_nontemporal_store(acc[fm][fn][j], op + (size_t)m * HD + n);
      }
}

extern "C" void kernel_launch(void* const* d_in, const int* in_sizes, int n_in,
                              void* d_out, int out_size, void* d_ws, size_t ws_size,
                              hipStream_t stream) {
  const float* x  = (const float*)d_in[0];
  const float* w1 = (const float*)d_in[1];
  const float* w2 = (const float*)d_in[2];
  float* out = (float*)d_out;
  unsigned short* hb = (unsigned short*)d_ws;   // h: E*CAP*F bf16 = 16.78 MB
  (void)in_sizes; (void)n_in; (void)out_size; (void)ws_size;

  moe_pass1<<<dim3(NE * 4), dim3(512), 0, stream>>>(x, w1, hb);
  moe_pass2<<<dim3(NE * 8), dim3(512), 0, stream>>>(hb, w2, out);
}

// Round 15
// 213.467 us; speedup vs baseline: 1.3200x; 1.0811x over previous
//
#include <hip/hip_runtime.h>

// SparseMLP (grouped GEMM MoE): out = gelu_tanh(x @ w1^T) @ w2, per expert.
// E=64, CAP=64, H=1024, F=2048, fp32 in/out.
// R15: OCCUPANCY. Evidence curve: 8 waves/CU -> 4.2 TB/s (R14), 16 -> 5.3
// (R6/R10/R11), 32 -> 7.05 (R12 read bench): latency-bound, linear in waves.
// Both passes re-tiled to 64x64x64, LDS 32KB/block, launch_bounds(512,6)
// -> 3 blocks/CU = 24 waves/CU (was 2 blocks/16 waves). Slim wave tile
// (32x16, acc=8 VGPR, single 2-deep staging set) keeps VGPR ~60 < 85 cap.
// Everything else = proven R6 template: nt w-loads, regular x/h loads &
// h stores, nt out stores, T1 XCD swizzle, T2 LDS XOR swizzle, T4 barriers.

typedef __attribute__((ext_vector_type(8))) short short8;    // 8 bf16 = 4 VGPR
typedef __attribute__((ext_vector_type(4))) float f32x4;     // MFMA acc / ld
typedef __attribute__((ext_vector_type(8))) unsigned short ushort8;

#define NE   64
#define CAPT 64
#define HD   1024
#define FD   2048

// fp32 -> bf16 round-to-nearest-even
__device__ __forceinline__ unsigned short f2bf(float f) {
  union { float f; unsigned u; } v; v.f = f;
  unsigned r = v.u + 0x7FFFu + ((v.u >> 16) & 1u);
  return (unsigned short)(r >> 16);
}

// gelu_tanh(v) = v * sigmoid(2*0.79788456*(v + 0.044715 v^3))  (exact rewrite)
__device__ __forceinline__ float gelu_t(float v) {
  float u = 1.5957691216057308f * (v + 0.044715f * v * v * v);
  return v / (1.0f + __expf(-u));
}

// XOR swizzle (T2) for a [rows][64]-bf16 tile (row stride 128B).
__device__ __forceinline__ int swz(int row, int kbyte) {
  return row * 128 + (kbyte ^ ((row & 7) << 4));
}

__device__ __forceinline__ void cvt_wr4(unsigned char* dst, f32x4 v) {
  uint2 p;
  p.x = (unsigned)f2bf(v.x) | ((unsigned)f2bf(v.y) << 16);
  p.y = (unsigned)f2bf(v.z) | ((unsigned)f2bf(v.w) << 16);
  *(uint2*)dst = p;   // ds_write_b64
}

// Raw barrier with LDS-only drain (T4): outstanding GLOBAL loads stay in
// flight across the barrier; register deps produce counted vmcnt waits.
__device__ __forceinline__ void tile_barrier() {
  asm volatile("s_waitcnt lgkmcnt(0)" ::: "memory");
  __builtin_amdgcn_s_barrier();
  __builtin_amdgcn_sched_barrier(0);
}

// Bijective XCD swizzle (T1): same-expert blocks share an L2.
__device__ __forceinline__ int xcd_swz(int bid, int grid) {
  return (bid & 7) * (grid >> 3) + (bid >> 3);
}

#define TSZ (64 * 128)   // one [64][64]-bf16 tile, bytes (8 KB)

// ---------------------------------------------------------------- pass 1 ---
// C1[64,2048] = x_e[64,1024] @ w1_e[2048,1024]^T  (NT: both K-contiguous)
// grid = E*32 = 2048; tile BM=64 BN=64 BK=64; 8 waves, wave tile 32x16.
// LDS 32KB -> 3 blocks/CU at launch_bounds(512,6) = 24 waves/CU.
__global__ __launch_bounds__(512, 6)
void moe_pass1(const float* __restrict__ x, const float* __restrict__ w1,
               unsigned short* __restrict__ hb) {
  __shared__ __align__(16) unsigned char sA[2 * TSZ];   // 16 KB
  __shared__ __align__(16) unsigned char sB[2 * TSZ];   // 16 KB
  const int bid = xcd_swz(blockIdx.x, NE * 32);
  const int e = bid >> 5, nb = bid & 31;
  const int t = threadIdx.x, lane = t & 63, wid = t >> 6;
  const int wm = wid >> 2, wn = wid & 3;
  const int lr = lane & 15, lk16 = (lane >> 4) * 16;

  const float* xg  = x  + (size_t)e * CAPT * HD;
  const float* w1g = w1 + ((size_t)e * FD + (size_t)nb * 64) * HD;

  f32x4 acc[2] = {};

  // staging: 64 rows x 16 chunks (16B f32x4) = 1024 units; 2/thread each.
  f32x4 ra[2], rb[2];
  auto loadT = [&](int k0) {
    #pragma unroll
    for (int i = 0; i < 2; ++i) {
      int u = t + i * 512;
      ra[i] = *(const f32x4*)(xg + (u >> 4) * HD + k0 + (u & 15) * 4);   // L2-reused
    }
    #pragma unroll
    for (int i = 0; i < 2; ++i) {
      int u = t + i * 512;
      rb[i] = __builtin_nontemporal_load(                                 // stream
          (const f32x4*)(w1g + (u >> 4) * HD + k0 + (u & 15) * 4));
    }
  };
  auto writeT = [&](unsigned char* a, unsigned char* b) {
    #pragma unroll
    for (int i = 0; i < 2; ++i) {
      int u = t + i * 512;
      cvt_wr4(a + swz(u >> 4, (u & 15) * 8), ra[i]);
    }
    #pragma unroll
    for (int i = 0; i < 2; ++i) {
      int u = t + i * 512;
      cvt_wr4(b + swz(u >> 4, (u & 15) * 8), rb[i]);
    }
  };

  const int NK = HD / 64;                      // 16 K-steps
  loadT(0);
  writeT(sA, sB);
  loadT(64);
  tile_barrier();

  int cur = 0;
  #pragma unroll 1
  for (int ks = 0; ks < NK; ++ks) {
    unsigned char* cA = sA + cur * TSZ;
    unsigned char* cB = sB + cur * TSZ;
    if (ks + 1 < NK) writeT(sA + (cur ^ 1) * TSZ, sB + (cur ^ 1) * TSZ);
    if (ks + 2 < NK) loadT((ks + 2) * 64);

    #pragma unroll
    for (int kk = 0; kk < 2; ++kk) {           // K=64 = 2 x 32
      short8 af0 = *(const short8*)(cA + swz(wm * 32 + lr,      kk * 64 + lk16));
      short8 af1 = *(const short8*)(cA + swz(wm * 32 + 16 + lr, kk * 64 + lk16));
      short8 bfr = *(const short8*)(cB + swz(wn * 16 + lr,      kk * 64 + lk16));
      acc[0] = __builtin_amdgcn_mfma_f32_16x16x32_bf16(af0, bfr, acc[0], 0, 0, 0);
      acc[1] = __builtin_amdgcn_mfma_f32_16x16x32_bf16(af1, bfr, acc[1], 0, 0, 0);
    }
    tile_barrier();
    cur ^= 1;
  }

  // epilogue: gelu, cvt bf16, store h. C/D map: col=lane&15, row=(lane>>4)*4+j
  unsigned short* hp = hb + (size_t)e * CAPT * FD + nb * 64;
  #pragma unroll
  for (int fm = 0; fm < 2; ++fm)
    #pragma unroll
    for (int j = 0; j < 4; ++j) {
      int m = wm * 32 + fm * 16 + (lane >> 4) * 4 + j;
      int f = wn * 16 + lr;
      hp[(size_t)m * FD + f] = f2bf(gelu_t(acc[fm][j]));
    }
}

// ---------------------------------------------------------------- pass 2 ---
// C2[64,1024] = h_e[64,2048](bf16) @ w2_e[2048,1024]  (NN: w2 transposed at
// stage time into LDS [n][k]). Tile BM=64 BN=64 BK=64, 3 blocks/CU.
__global__ __launch_bounds__(512, 6)
void moe_pass2(const unsigned short* __restrict__ hb, const float* __restrict__ w2,
               float* __restrict__ out) {
  __shared__ __align__(16) unsigned char sA[2 * TSZ];   // 16 KB (h)
  __shared__ __align__(16) unsigned char sB[2 * TSZ];   // 16 KB ([n][k] w2)
  const int bid = xcd_swz(blockIdx.x, NE * 16);
  const int e = bid >> 4, nb = bid & 15;
  const int t = threadIdx.x, lane = t & 63, wid = t >> 6;
  const int wm = wid >> 2, wn = wid & 3;
  const int lr = lane & 15, lk16 = (lane >> 4) * 16;

  const unsigned short* hg = hb + (size_t)e * CAPT * FD;
  const float* w2g = w2 + (size_t)e * FD * HD + nb * 64;

  f32x4 acc[2] = {};

  const int ar = t >> 3, ac = t & 7;     // A: 512 ushort8 units, 1/thread
  const int bn = t & 63, bkg = t >> 6;   // B: lane owns col n, k-group of 8

  ushort8 rav;
  float rbv[8];
  auto loadT = [&](int f0) {
    rav = *(const ushort8*)(hg + (size_t)ar * FD + f0 + ac * 8);          // L2/L3-warm
    #pragma unroll
    for (int j = 0; j < 8; ++j)
      rbv[j] = __builtin_nontemporal_load(                                 // stream
          w2g + (size_t)(f0 + bkg * 8 + j) * HD + bn);
  };
  auto writeT = [&](unsigned char* a, unsigned char* b) {
    *(ushort8*)(a + swz(ar, ac * 16)) = rav;           // ds_write_b128
    #pragma unroll
    for (int i = 0; i < 2; ++i) {                      // transposed b64 writes
      uint2 p;
      p.x = (unsigned)f2bf(rbv[i * 4 + 0]) | ((unsigned)f2bf(rbv[i * 4 + 1]) << 16);
      p.y = (unsigned)f2bf(rbv[i * 4 + 2]) | ((unsigned)f2bf(rbv[i * 4 + 3]) << 16);
      *(uint2*)(b + swz(bn, bkg * 16 + i * 8)) = p;
    }
  };

  const int NK = FD / 64;                      // 32 K-steps
  loadT(0);
  writeT(sA, sB);
  loadT(64);
  tile_barrier();

  int cur = 0;
  #pragma unroll 1
  for (int ks = 0; ks < NK; ++ks) {
    unsigned char* cA = sA + cur * TSZ;
    unsigned char* cB = sB + cur * TSZ;
    if (ks + 1 < NK) writeT(sA + (cur ^ 1) * TSZ, sB + (cur ^ 1) * TSZ);
    if (ks + 2 < NK) loadT((ks + 2) * 64);

    #pragma unroll
    for (int kk = 0; kk < 2; ++kk) {
      short8 af0 = *(const short8*)(cA + swz(wm * 32 + lr,      kk * 64 + lk16));
      short8 af1 = *(const short8*)(cA + swz(wm * 32 + 16 + lr, kk * 64 + lk16));
      short8 bfr = *(const short8*)(cB + swz(wn * 16 + lr,      kk * 64 + lk16));
      acc[0] = __builtin_amdgcn_mfma_f32_16x16x32_bf16(af0, bfr, acc[0], 0, 0, 0);
      acc[1] = __builtin_amdgcn_mfma_f32_16x16x32_bf16(af1, bfr, acc[1], 0, 0, 0);
    }
    tile_barrier();
    cur ^= 1;
  }

  float* op = out + (size_t)e * CAPT * HD + nb * 64;
  #pragma unroll
  for (int fm = 0; fm < 2; ++fm)
    #pragma unroll
    for (int j = 0; j < 4; ++j) {
      int m = wm * 32 + fm * 16 + (lane >> 4) * 4 + j;
      int n = wn * 16 + lr;
      __builtin_nontemporal_store(acc[fm][j], op + (size_t)m * HD + n);
    }
}

extern "C" void kernel_launch(void* const* d_in, const int* in_sizes, int n_in,
                              void* d_out, int out_size, void* d_ws, size_t ws_size,
                              hipStream_t stream) {
  const float* x  = (const float*)d_in[0];
  const float* w1 = (const float*)d_in[1];
  const float* w2 = (const float*)d_in[2];
  float* out = (float*)d_out;
  unsigned short* hb = (unsigned short*)d_ws;   // h: E*CAP*F bf16 = 16.78 MB
  (void)in_sizes; (void)n_in; (void)out_size; (void)ws_size;

  moe_pass1<<<dim3(NE * 32), dim3(512), 0, stream>>>(x, w1, hb);
  moe_pass2<<<dim3(NE * 16), dim3(512), 0, stream>>>(hb, w2, out);
}